// Round 7
// baseline (142.632 us; speedup 1.0000x reference)
//
#include <hip/hip_runtime.h>

// Problem constants
#define BSZ 16
#define NN  128
#define HH  256
#define LLG 9
#define FFE 48   // edge feature dim (padded to 64 for MFMA K)
#define JC  64   // j-chunk size (2 chunks of 64)

typedef float        f32x4 __attribute__((ext_vector_type(4)));
typedef _Float16     f16x8 __attribute__((ext_vector_type(8)));
typedef unsigned int u32x4 __attribute__((ext_vector_type(4)));

static __device__ __forceinline__ unsigned short f2h_bits(float x) {
    _Float16 h = (_Float16)x;   // RNE
    return __builtin_bit_cast(unsigned short, h);
}

static __device__ __forceinline__ float fast_silu(float x) {
    float e = __builtin_amdgcn_exp2f(x * -1.44269504088896341f);
    return x * __builtin_amdgcn_rcpf(1.0f + e);
}

// ---------------------------------------------------------------------------
// Kernel 1: weight transpose + f32->f16 convert.  (proven)
//   WeT[h][f]  (256 x 64, f>=48 zero-padded)  from W1 rows 521..568
//   W2T[ho][k] (256 x 256)                    from W2[k][ho]
// ---------------------------------------------------------------------------
__global__ __launch_bounds__(256) void pre_w(
    const float* __restrict__ W1, const float* __restrict__ W2,
    unsigned short* __restrict__ W2T, unsigned short* __restrict__ WeT)
{
    int tid = blockIdx.x * 256 + threadIdx.x;   // grid 256 -> 65536 threads
    {
        int ho = tid >> 8, k = tid & 255;
        W2T[(ho << 8) + k] = f2h_bits(W2[(k << 8) + ho]);  // coalesced write
    }
    if (tid < 256 * 64) {
        int h = tid >> 6, f = tid & 63;
        WeT[(h << 6) + f] = (f < FFE) ? f2h_bits(W1[(521 + f) * HH + h])
                                      : (unsigned short)0;
    }
}

// ---------------------------------------------------------------------------
// Kernel 2: pj[b,r,h] = node@Wj ; base[b,r,h] = node@Wi + graph@Wg + b1 (proven)
// ---------------------------------------------------------------------------
__global__ __launch_bounds__(256) void pre_pjbase(
    const float* __restrict__ node, const float* __restrict__ graph,
    const float* __restrict__ W1, const float* __restrict__ b1,
    float* __restrict__ pj, float* __restrict__ base)
{
    __shared__ float nrow[4][HH];
    __shared__ float gsh[LLG];
    const int blk = blockIdx.x;
    const int b = blk >> 5;             // 32 row-groups of 4 per batch
    const int r0 = (blk & 31) << 2;
    const int h = threadIdx.x;

    for (int t = h; t < 4 * HH; t += 256) {
        int r = t >> 8, k = t & 255;
        nrow[r][k] = node[(((size_t)b * NN) + r0 + r) * HH + k];
    }
    if (h < LLG) gsh[h] = graph[b * LLG + h];
    __syncthreads();

    float accj[4] = {0,0,0,0};
    float acci[4] = {0,0,0,0};
    for (int k = 0; k < HH; ++k) {
        float wj = W1[k * HH + h];
        float wi = W1[(k + HH) * HH + h];
        #pragma unroll
        for (int r = 0; r < 4; ++r) {
            float nv = nrow[r][k];
            accj[r] = fmaf(nv, wj, accj[r]);
            acci[r] = fmaf(nv, wi, acci[r]);
        }
    }
    float accg = b1[h];
    #pragma unroll
    for (int l = 0; l < LLG; ++l)
        accg = fmaf(gsh[l], W1[(2 * HH + l) * HH + h], accg);

    #pragma unroll
    for (int r = 0; r < 4; ++r) {
        size_t off = (((size_t)b * NN) + r0 + r) * HH + h;
        pj[off]   = accj[r];
        base[off] = acci[r] + accg;
    }
}

// ---------------------------------------------------------------------------
// Kernel 3: fused main. One block per (b,i); 8 waves; j in 2 chunks of 64.
// LDS = h1s 32 KB + efs 8 KB = 40 KB -> 3-4 blocks/CU (vs 2 at round 5).
// Round-5 per-wave structure kept (epilogue adds, no C-init, no prefetch);
// chunk-1 edge staging is T14-split (loads issued before GEMM2(0), LDS
// writes after) so its HBM latency hides under 64 MFMAs.
// ---------------------------------------------------------------------------
__global__ __launch_bounds__(512, 4) void fused_msg(
    const float* __restrict__ edge, const float* __restrict__ pj,
    const float* __restrict__ base, const unsigned short* __restrict__ W2T,
    const unsigned short* __restrict__ WeT, const float* __restrict__ b2,
    float* __restrict__ out)
{
    __shared__ unsigned char h1s[JC * HH * 2];   // 32 KB: h1[jc][h] f16, swizzled
    __shared__ unsigned char efs[JC * 64 * 2];   //  8 KB: edge[jc][f] f16, padded+swizzled
    const int tid  = threadIdx.x;
    const int w    = tid >> 6;         // wave 0..7
    const int lane = tid & 63;
    const int q    = lane >> 4;        // quad 0..3
    const int c    = lane & 15;
    const int bi   = blockIdx.x;       // b*128 + i
    const int b    = bi >> 7;

    const float* eb = edge + (size_t)bi * (NN * FFE);

    float b2v[2];
    #pragma unroll
    for (int nt = 0; nt < 2; ++nt) b2v[nt] = b2[(w << 5) + (nt << 4) + c];
    float s[2] = {0.f, 0.f};

    // convert one float4 of edge to f16 and write to swizzled efs slot
    auto stage_write = [&](f32x4 x, int e4) {
        const int j  = e4 / 12;                  // 12 float4 per 48-float row
        const int f4 = e4 - j * 12;              // 0..11
        unsigned int lo = __builtin_bit_cast(unsigned int,
                            __builtin_amdgcn_cvt_pkrtz(x[0], x[1]));
        unsigned int hi = __builtin_bit_cast(unsigned int,
                            __builtin_amdgcn_cvt_pkrtz(x[2], x[3]));
        const unsigned int off = (unsigned)(j << 7) +
            (((unsigned)(f4 << 3)) ^ ((unsigned)(j & 7) << 4));
        *reinterpret_cast<uint2*>(&efs[off]) = make_uint2(lo, hi);
    };

    // zero-fill padded f in [48,64) once (never overwritten by staging)
    if (tid < 256) {
        const int j = tid >> 2, g = tid & 3;
        const unsigned int off = (unsigned)(j << 7) +
            (((unsigned)(96 + (g << 3))) ^ ((unsigned)(j & 7) << 4));
        *reinterpret_cast<uint2*>(&efs[off]) = make_uint2(0u, 0u);
    }

    // stage chunk 0: 64 rows x 48 floats = 768 float4 over 512 threads
    {
        f32x4 xa = *reinterpret_cast<const f32x4*>(eb + (tid << 2));
        stage_write(xa, tid);
        if (tid < 256) {
            f32x4 xb = *reinterpret_cast<const f32x4*>(eb + ((512 + tid) << 2));
            stage_write(xb, 512 + tid);
        }
    }
    __syncthreads();   // bar1: efs(0) ready

    // GEMM1 + epilogue1 for one chunk: D1[h(32), jc(64)] -> silu -> h1s
    auto gemm1 = [&](int chunk) {
        f32x4 acc1[2][4];
        #pragma unroll
        for (int mt = 0; mt < 2; ++mt)
            #pragma unroll
            for (int nt = 0; nt < 4; ++nt) acc1[mt][nt] = f32x4{0.f, 0.f, 0.f, 0.f};

        #pragma unroll
        for (int kk = 0; kk < 2; ++kk) {
            const int koff = (kk << 5) + (q << 3);   // f16-units f offset
            const int fb   = koff << 1;              // byte offset in efs row
            f16x8 af[2];
            #pragma unroll
            for (int mt = 0; mt < 2; ++mt) {
                const int row = (w << 5) + (mt << 4) + c;       // h
                af[mt] = *reinterpret_cast<const f16x8*>(WeT + (row << 6) + koff);
            }
            #pragma unroll
            for (int nt = 0; nt < 4; ++nt) {
                const int j = (nt << 4) + c;                    // local jc
                const f16x8 bf = *reinterpret_cast<const f16x8*>(
                    &efs[(unsigned)(j << 7) +
                         (((unsigned)fb) ^ ((unsigned)(j & 7) << 4))]);
                #pragma unroll
                for (int mt = 0; mt < 2; ++mt)
                    acc1[mt][nt] = __builtin_amdgcn_mfma_f32_16x16x32_f16(
                        af[mt], bf, acc1[mt][nt], 0, 0, 0);
            }
        }

        // epilogue 1: z1 = D1 + base + pj -> silu -> f16 -> h1s (swizzled)
        #pragma unroll
        for (int mt = 0; mt < 2; ++mt) {
            const int h0 = (w << 5) + (mt << 4) + (q << 2);
            const f32x4 bb = *reinterpret_cast<const f32x4*>(
                base + ((size_t)bi << 8) + h0);
            #pragma unroll
            for (int nt = 0; nt < 4; ++nt) {
                const int jc = (nt << 4) + c;
                const int jg = (chunk << 6) + jc;
                const f32x4 pjv = *reinterpret_cast<const f32x4*>(
                    pj + (((size_t)b << 7) + jg) * HH + h0);
                float s0 = fast_silu(acc1[mt][nt][0] + bb[0] + pjv[0]);
                float s1 = fast_silu(acc1[mt][nt][1] + bb[1] + pjv[1]);
                float s2 = fast_silu(acc1[mt][nt][2] + bb[2] + pjv[2]);
                float s3 = fast_silu(acc1[mt][nt][3] + bb[3] + pjv[3]);
                unsigned int lo = __builtin_bit_cast(unsigned int,
                                    __builtin_amdgcn_cvt_pkrtz(s0, s1));
                unsigned int hi = __builtin_bit_cast(unsigned int,
                                    __builtin_amdgcn_cvt_pkrtz(s2, s3));
                const unsigned int off = (unsigned)(jc << 9) +
                    (((unsigned)(h0 << 1)) ^ ((unsigned)(jc & 7) << 4));
                *reinterpret_cast<uint2*>(&h1s[off]) = make_uint2(lo, hi);
            }
        }
    };

    // GEMM2 for one chunk: D2[jc(64), ho(32)]; silu + j-partial sums into s[]
    auto gemm2 = [&]() {
        f32x4 acc2[4][2];
        #pragma unroll
        for (int m = 0; m < 4; ++m)
            #pragma unroll
            for (int nt = 0; nt < 2; ++nt) acc2[m][nt] = f32x4{0.f, 0.f, 0.f, 0.f};

        const unsigned short* wp0 = W2T + (((w << 5) + c) << 8) + (q << 3);
        const unsigned short* wp1 = wp0 + (16 << 8);

        #pragma unroll 2
        for (int kk = 0; kk < 8; ++kk) {
            const f16x8 bw0 = *reinterpret_cast<const f16x8*>(wp0 + (kk << 5));
            const f16x8 bw1 = *reinterpret_cast<const f16x8*>(wp1 + (kk << 5));
            const int kb = (kk << 6) + (q << 4);     // byte offset of k-slice
            f16x8 a2[4];
            #pragma unroll
            for (int m = 0; m < 4; ++m) {
                const int jc = (m << 4) + c;
                const unsigned int off = (unsigned)(jc << 9) +
                    (((unsigned)kb) ^ ((unsigned)(jc & 7) << 4));
                a2[m] = *reinterpret_cast<const f16x8*>(&h1s[off]);
            }
            #pragma unroll
            for (int m = 0; m < 4; ++m) {
                acc2[m][0] = __builtin_amdgcn_mfma_f32_16x16x32_f16(
                    a2[m], bw0, acc2[m][0], 0, 0, 0);
                acc2[m][1] = __builtin_amdgcn_mfma_f32_16x16x32_f16(
                    a2[m], bw1, acc2[m][1], 0, 0, 0);
            }
        }

        #pragma unroll
        for (int nt = 0; nt < 2; ++nt)
            #pragma unroll
            for (int m = 0; m < 4; ++m)
                #pragma unroll
                for (int r = 0; r < 4; ++r)
                    s[nt] += fast_silu(acc2[m][nt][r] + b2v[nt]);
    };

    // ---- chunk 0 ----
    gemm1(0);
    __syncthreads();   // bar2: h1s(0) ready, efs(0) consumed

    // T14 split: issue chunk-1 edge loads now; they drain under GEMM2(0)
    f32x4 xa = *reinterpret_cast<const f32x4*>(eb + 3072 + (tid << 2));
    f32x4 xb = {0.f, 0.f, 0.f, 0.f};
    if (tid < 256)
        xb = *reinterpret_cast<const f32x4*>(eb + 3072 + ((512 + tid) << 2));

    gemm2();           // chunk-0 GEMM2 (reads h1s only)

    stage_write(xa, tid);                  // efs(1) writes (efs free since bar2)
    if (tid < 256) stage_write(xb, 512 + tid);
    __syncthreads();   // bar3: efs(1) ready, h1s(0) consumed

    // ---- chunk 1 ----
    gemm1(1);
    __syncthreads();   // bar4: h1s(1) ready
    gemm2();

    // butterfly across quads, store
    #pragma unroll
    for (int nt = 0; nt < 2; ++nt) {
        s[nt] += __shfl_xor(s[nt], 16);
        s[nt] += __shfl_xor(s[nt], 32);
    }
    if (q < 2)
        out[((size_t)bi << 8) + (w << 5) + (q << 4) + c] = s[q] * 0.0078125f;
}

// ---------------------------------------------------------------------------
extern "C" void kernel_launch(void* const* d_in, const int* in_sizes, int n_in,
                              void* d_out, int out_size, void* d_ws, size_t ws_size,
                              hipStream_t stream)
{
    const float* node  = (const float*)d_in[0];
    const float* edge  = (const float*)d_in[1];
    const float* graph = (const float*)d_in[2];
    const float* W1    = (const float*)d_in[3];
    const float* b1    = (const float*)d_in[4];
    const float* W2    = (const float*)d_in[5];
    const float* b2    = (const float*)d_in[6];
    float* out = (float*)d_out;

    char* ws = (char*)d_ws;
    unsigned short* W2T = (unsigned short*)ws;              // 131072 B
    unsigned short* WeT = (unsigned short*)(ws + 131072);   //  32768 B
    float* pj   = (float*)(ws + 163840);                    // 2 MB
    float* base = (float*)(ws + 163840 + 2097152);          // 2 MB

    pre_w     <<<256, 256, 0, stream>>>(W1, W2, W2T, WeT);
    pre_pjbase<<<512, 256, 0, stream>>>(node, graph, W1, b1, pj, base);
    fused_msg <<<BSZ * NN, 512, 0, stream>>>(edge, pj, base, W2T, WeT, b2, out);
}

// Round 8
// 110.619 us; speedup vs baseline: 1.2894x; 1.2894x over previous
//
#include <hip/hip_runtime.h>

// Problem constants
#define BSZ 16
#define NN  128
#define HH  256
#define LLG 9
#define FFE 48   // edge feature dim (padded to 64 for MFMA K)

typedef float        f32x4 __attribute__((ext_vector_type(4)));
typedef _Float16     f16x8 __attribute__((ext_vector_type(8)));
typedef unsigned int u32x4 __attribute__((ext_vector_type(4)));

static __device__ __forceinline__ unsigned short f2h_bits(float x) {
    _Float16 h = (_Float16)x;   // RNE
    return __builtin_bit_cast(unsigned short, h);
}

static __device__ __forceinline__ float fast_silu(float x) {
    float e = __builtin_amdgcn_exp2f(x * -1.44269504088896341f);
    return x * __builtin_amdgcn_rcpf(1.0f + e);
}

// ---------------------------------------------------------------------------
// Kernel 1: weight transpose + f32->f16 convert.  (proven)
// ---------------------------------------------------------------------------
__global__ __launch_bounds__(256) void pre_w(
    const float* __restrict__ W1, const float* __restrict__ W2,
    unsigned short* __restrict__ W2T, unsigned short* __restrict__ WeT)
{
    int tid = blockIdx.x * 256 + threadIdx.x;   // grid 256 -> 65536 threads
    {
        int ho = tid >> 8, k = tid & 255;
        W2T[(ho << 8) + k] = f2h_bits(W2[(k << 8) + ho]);  // coalesced write
    }
    if (tid < 256 * 64) {
        int h = tid >> 6, f = tid & 63;
        WeT[(h << 6) + f] = (f < FFE) ? f2h_bits(W1[(521 + f) * HH + h])
                                      : (unsigned short)0;
    }
}

// ---------------------------------------------------------------------------
// Kernel 2: pj[b,r,h] = node@Wj ; base[b,r,h] = node@Wi + graph@Wg + b1 (proven)
// ---------------------------------------------------------------------------
__global__ __launch_bounds__(256) void pre_pjbase(
    const float* __restrict__ node, const float* __restrict__ graph,
    const float* __restrict__ W1, const float* __restrict__ b1,
    float* __restrict__ pj, float* __restrict__ base)
{
    __shared__ float nrow[4][HH];
    __shared__ float gsh[LLG];
    const int blk = blockIdx.x;
    const int b = blk >> 5;             // 32 row-groups of 4 per batch
    const int r0 = (blk & 31) << 2;
    const int h = threadIdx.x;

    for (int t = h; t < 4 * HH; t += 256) {
        int r = t >> 8, k = t & 255;
        nrow[r][k] = node[(((size_t)b * NN) + r0 + r) * HH + k];
    }
    if (h < LLG) gsh[h] = graph[b * LLG + h];
    __syncthreads();

    float accj[4] = {0,0,0,0};
    float acci[4] = {0,0,0,0};
    for (int k = 0; k < HH; ++k) {
        float wj = W1[k * HH + h];
        float wi = W1[(k + HH) * HH + h];
        #pragma unroll
        for (int r = 0; r < 4; ++r) {
            float nv = nrow[r][k];
            accj[r] = fmaf(nv, wj, accj[r]);
            acci[r] = fmaf(nv, wi, acci[r]);
        }
    }
    float accg = b1[h];
    #pragma unroll
    for (int l = 0; l < LLG; ++l)
        accg = fmaf(gsh[l], W1[(2 * HH + l) * HH + h], accg);

    #pragma unroll
    for (int r = 0; r < 4; ++r) {
        size_t off = (((size_t)b * NN) + r0 + r) * HH + h;
        pj[off]   = accj[r];
        base[off] = acci[r] + accg;
    }
}

// ---------------------------------------------------------------------------
// Kernel 3: fused main — round-5 structure (best: 92 us), with
//  (1) all LDS offsets decomposed to per-thread base + compile-time
//      immediate (jc&7 == c&7 is lane-constant, so the XOR swizzle term
//      folds into 2 precomputed bases per access family), and
//  (2) s_setprio(1/0) around GEMM2 MFMA clusters (T5; 2 desynced blocks/CU).
// ---------------------------------------------------------------------------
__global__ __launch_bounds__(512, 4) void fused_msg(
    const float* __restrict__ edge, const float* __restrict__ pj,
    const float* __restrict__ base, const unsigned short* __restrict__ W2T,
    const unsigned short* __restrict__ WeT, const float* __restrict__ b2,
    float* __restrict__ out)
{
    __shared__ unsigned char h1s[NN * HH * 2];   // 64 KB: h1[j][h] f16, swizzled
    __shared__ unsigned char efs[NN * 64 * 2];   // 16 KB: edge[j][f] f16, padded+swizzled
    const int tid  = threadIdx.x;
    const int w    = tid >> 6;         // wave 0..7
    const int lane = tid & 63;
    const int q    = lane >> 4;        // quad 0..3
    const int c    = lane & 15;
    const int bi   = blockIdx.x;       // b*128 + i
    const int b    = bi >> 7;

    const float* eb = edge + (size_t)bi * (NN * FFE);
    const unsigned ck = (unsigned)(c & 7) << 4;      // lane-constant XOR key

    // ---- stage edge block -> f16 LDS, row-padded to 64 f16, XOR-swizzled ----
    #pragma unroll
    for (int p = 0; p < 3; ++p) {
        const int e4 = p * 512 + tid;            // float4 index, < 1536
        const int j  = e4 / 12;                  // 12 float4 per 48-float row
        const int f4 = e4 - j * 12;              // 0..11
        const f32x4 x = *reinterpret_cast<const f32x4*>(eb + (e4 << 2));
        unsigned int lo = __builtin_bit_cast(unsigned int,
                            __builtin_amdgcn_cvt_pkrtz(x[0], x[1]));
        unsigned int hi = __builtin_bit_cast(unsigned int,
                            __builtin_amdgcn_cvt_pkrtz(x[2], x[3]));
        const unsigned int off = (unsigned)(j << 7) +
            (((unsigned)(f4 << 3)) ^ ((unsigned)(j & 7) << 4));
        *reinterpret_cast<uint2*>(&efs[off]) = make_uint2(lo, hi);
    }
    {   // zero-fill padded f in [48,64)
        const int j = tid >> 2, g = tid & 3;
        const unsigned int off = (unsigned)(j << 7) +
            (((unsigned)(96 + (g << 3))) ^ ((unsigned)(j & 7) << 4));
        *reinterpret_cast<uint2*>(&efs[off]) = make_uint2(0u, 0u);
    }
    __syncthreads();

    // ---- per-thread LDS base offsets (all loop-varying parts are immediates)
    // GEMM1 efs reads:  off = ge[kk] + nt*2048
    const unsigned ge0 = (unsigned)(c << 7) + (((unsigned)(q << 4)) ^ ck);
    const unsigned ge1 = (unsigned)(c << 7) + (((unsigned)(64 | (q << 4))) ^ ck);
    // epi1 h1s writes:  off = we[mt] + nt*8192
    const unsigned we0 = (unsigned)(c << 9) +
        (((unsigned)((w << 6) | (q << 3))) ^ ck);
    const unsigned we1 = (unsigned)(c << 9) +
        (((unsigned)((w << 6) | 32 | (q << 3))) ^ ck);
    // GEMM2 h1s reads:  off = gr[kk&1] + (kk>>1)*128 + M*8192   (M = 0..7)
    const unsigned gr0 = (unsigned)(c << 9) + (((unsigned)(q << 4)) ^ ck);
    const unsigned gr1 = (unsigned)(c << 9) + (((unsigned)(64 | (q << 4))) ^ ck);

    // ------------------ GEMM1: D1[h(32), j(128)] ------------------
    f32x4 acc1[2][8];
    #pragma unroll
    for (int mt = 0; mt < 2; ++mt)
        #pragma unroll
        for (int nt = 0; nt < 8; ++nt) acc1[mt][nt] = f32x4{0.f, 0.f, 0.f, 0.f};

    #pragma unroll
    for (int kk = 0; kk < 2; ++kk) {
        const int koff = (kk << 5) + (q << 3);   // f16-units f offset
        const unsigned geb = kk ? ge1 : ge0;
        f16x8 af[2];
        #pragma unroll
        for (int mt = 0; mt < 2; ++mt) {
            const int row = (w << 5) + (mt << 4) + c;       // h
            af[mt] = *reinterpret_cast<const f16x8*>(WeT + (row << 6) + koff);
        }
        #pragma unroll
        for (int nt = 0; nt < 8; ++nt) {
            const f16x8 bf = *reinterpret_cast<const f16x8*>(
                &efs[geb + (unsigned)(nt << 11)]);
            #pragma unroll
            for (int mt = 0; mt < 2; ++mt)
                acc1[mt][nt] = __builtin_amdgcn_mfma_f32_16x16x32_f16(
                    af[mt], bf, acc1[mt][nt], 0, 0, 0);
        }
    }

    // epilogue 1: z1 -> silu -> f16 -> h1s (base + immediate offsets)
    #pragma unroll
    for (int mt = 0; mt < 2; ++mt) {
        const int h0 = (w << 5) + (mt << 4) + (q << 2);
        const unsigned web = mt ? we1 : we0;
        const f32x4 bb = *reinterpret_cast<const f32x4*>(
            base + ((size_t)bi << 8) + h0);
        #pragma unroll
        for (int nt = 0; nt < 8; ++nt) {
            const int jc = (nt << 4) + c;
            const f32x4 pjv = *reinterpret_cast<const f32x4*>(
                pj + (((size_t)b << 7) + jc) * HH + h0);
            float s0 = fast_silu(acc1[mt][nt][0] + bb[0] + pjv[0]);
            float s1 = fast_silu(acc1[mt][nt][1] + bb[1] + pjv[1]);
            float s2 = fast_silu(acc1[mt][nt][2] + bb[2] + pjv[2]);
            float s3 = fast_silu(acc1[mt][nt][3] + bb[3] + pjv[3]);
            unsigned int lo = __builtin_bit_cast(unsigned int,
                                __builtin_amdgcn_cvt_pkrtz(s0, s1));
            unsigned int hi = __builtin_bit_cast(unsigned int,
                                __builtin_amdgcn_cvt_pkrtz(s2, s3));
            *reinterpret_cast<uint2*>(&h1s[web + (unsigned)(nt << 13)]) =
                make_uint2(lo, hi);
        }
    }
    __syncthreads();

    // ------------------ GEMM2: D2[jc(128), ho(32)] ------------------
    f32x4 acc2[8][2];
    #pragma unroll
    for (int mt = 0; mt < 8; ++mt)
        #pragma unroll
        for (int nt = 0; nt < 2; ++nt) acc2[mt][nt] = f32x4{0.f, 0.f, 0.f, 0.f};

    const unsigned short* wp0 = W2T + (((w << 5) + c) << 8) + (q << 3);
    const unsigned short* wp1 = wp0 + (16 << 8);

    #pragma unroll 2
    for (int kk = 0; kk < 8; ++kk) {
        const f16x8 bw0 = *reinterpret_cast<const f16x8*>(wp0 + (kk << 5));
        const f16x8 bw1 = *reinterpret_cast<const f16x8*>(wp1 + (kk << 5));
        const unsigned grb = ((kk & 1) ? gr1 : gr0) + (unsigned)((kk >> 1) << 7);
        #pragma unroll
        for (int g = 0; g < 2; ++g) {
            f16x8 a2[4];
            #pragma unroll
            for (int m = 0; m < 4; ++m) {
                const unsigned M = (unsigned)((g << 2) + m);
                a2[m] = *reinterpret_cast<const f16x8*>(&h1s[grb + (M << 13)]);
            }
            __builtin_amdgcn_s_setprio(1);
            #pragma unroll
            for (int m = 0; m < 4; ++m) {
                acc2[(g << 2) + m][0] = __builtin_amdgcn_mfma_f32_16x16x32_f16(
                    a2[m], bw0, acc2[(g << 2) + m][0], 0, 0, 0);
                acc2[(g << 2) + m][1] = __builtin_amdgcn_mfma_f32_16x16x32_f16(
                    a2[m], bw1, acc2[(g << 2) + m][1], 0, 0, 0);
            }
            __builtin_amdgcn_s_setprio(0);
        }
    }

    // epilogue 2: silu + j-sum, butterfly across quads, store
    float b2v[2];
    #pragma unroll
    for (int nt = 0; nt < 2; ++nt) b2v[nt] = b2[(w << 5) + (nt << 4) + c];

    float s[2] = {0.f, 0.f};
    #pragma unroll
    for (int nt = 0; nt < 2; ++nt)
        #pragma unroll
        for (int mt = 0; mt < 8; ++mt)
            #pragma unroll
            for (int r = 0; r < 4; ++r)
                s[nt] += fast_silu(acc2[mt][nt][r] + b2v[nt]);

    #pragma unroll
    for (int nt = 0; nt < 2; ++nt) {
        s[nt] += __shfl_xor(s[nt], 16);
        s[nt] += __shfl_xor(s[nt], 32);
    }
    if (q < 2)
        out[((size_t)bi << 8) + (w << 5) + (q << 4) + c] = s[q] * 0.0078125f;
}

// ---------------------------------------------------------------------------
extern "C" void kernel_launch(void* const* d_in, const int* in_sizes, int n_in,
                              void* d_out, int out_size, void* d_ws, size_t ws_size,
                              hipStream_t stream)
{
    const float* node  = (const float*)d_in[0];
    const float* edge  = (const float*)d_in[1];
    const float* graph = (const float*)d_in[2];
    const float* W1    = (const float*)d_in[3];
    const float* b1    = (const float*)d_in[4];
    const float* W2    = (const float*)d_in[5];
    const float* b2    = (const float*)d_in[6];
    float* out = (float*)d_out;

    char* ws = (char*)d_ws;
    unsigned short* W2T = (unsigned short*)ws;              // 131072 B
    unsigned short* WeT = (unsigned short*)(ws + 131072);   //  32768 B
    float* pj   = (float*)(ws + 163840);                    // 2 MB
    float* base = (float*)(ws + 163840 + 2097152);          // 2 MB

    pre_w     <<<256, 256, 0, stream>>>(W1, W2, W2T, WeT);
    pre_pjbase<<<512, 256, 0, stream>>>(node, graph, W1, b1, pj, base);
    fused_msg <<<BSZ * NN, 512, 0, stream>>>(edge, pj, base, W2T, WeT, b2, out);
}